// Round 1
// 423.070 us; speedup vs baseline: 1.1856x; 1.1856x over previous
//
#include <hip/hip_runtime.h>
#include <hip/hip_bf16.h>
#include <cstdint>
#include <cstddef>

#define C_CLS   100000
#define D_FEAT  512
#define B_ROWS  512
#define NBN     782          /* ceil(100000/128) */

#define COSM 0.8775825618903728f
#define SINM 0.479425538604203f
#define TH_  (-0.8775825618903728f)
#define MM_  0.2397127693021015f   /* sin(0.5)*0.5 */

typedef __bf16 bf16x8 __attribute__((ext_vector_type(8)));
typedef __bf16 bf16x4 __attribute__((ext_vector_type(4)));
typedef float  f32x4  __attribute__((ext_vector_type(4)));

typedef __attribute__((address_space(3))) void lds_void;
typedef const __attribute__((address_space(1))) void g_void;

__device__ __forceinline__ void async_copy16(const void* g, void* l) {
    __builtin_amdgcn_global_load_lds((g_void*)g, (lds_void*)l, 16, 0, 0);
}

// ---------------- kernel 1: normalize x rows -> bf16, zero output --------
__global__ void k_xnorm(const float* __restrict__ x, __bf16* __restrict__ xn,
                        float* __restrict__ out) {
    const int row  = blockIdx.x;          // 512 blocks
    const int lane = threadIdx.x;         // 64 threads
    if (row == 0 && lane == 0) out[0] = 0.0f;
    const f32x4* p = (const f32x4*)(x + (size_t)row * D_FEAT);
    f32x4 a = p[lane];
    f32x4 b = p[lane + 64];
    float s = a[0]*a[0] + a[1]*a[1] + a[2]*a[2] + a[3]*a[3]
            + b[0]*b[0] + b[1]*b[1] + b[2]*b[2] + b[3]*b[3];
    #pragma unroll
    for (int m = 32; m >= 1; m >>= 1) s += __shfl_xor(s, m, 64);
    const float inv = 1.0f / fmaxf(sqrtf(s), 1e-12f);
    bf16x4 o0 = { (__bf16)(a[0]*inv), (__bf16)(a[1]*inv), (__bf16)(a[2]*inv), (__bf16)(a[3]*inv) };
    bf16x4 o1 = { (__bf16)(b[0]*inv), (__bf16)(b[1]*inv), (__bf16)(b[2]*inv), (__bf16)(b[3]*inv) };
    *(bf16x4*)(xn + (size_t)row * D_FEAT + lane * 4)       = o0;
    *(bf16x4*)(xn + (size_t)row * D_FEAT + 256 + lane * 4) = o1;
}

// ---------------- kernel 2: single-pass MFMA GEMM ------------------------
// - weight norms computed inline from the fp32 values already staged in LDS
//   (replaces the whole k_wnorm 205 MB HBM pass)
// - double-buffered LDS, counted vmcnt(6) (never drains the async queue in
//   the main loop), raw s_barrier (T3-minimum 2-phase template)
// - deterministic psum[row][bn] partials instead of contended atomics
__global__ __launch_bounds__(256, 3) void k_gemm(
        const __bf16* __restrict__ xn, const float* __restrict__ w,
        const int* __restrict__ y,
        float* __restrict__ psum, float* __restrict__ tlogit) {

    __shared__ __align__(16) __bf16 As[2][4096];   // [buf][quad][row][8] :  16 KB
    __shared__ __align__(16) float  Bs[2][4096];   // [buf][quad][row][8] :  32 KB
    __shared__ int   ys[128];
    __shared__ float red[2][128];

    const int tid = threadIdx.x;
    const int bm  = blockIdx.x & 3;
    const int bn  = blockIdx.x >> 2;

    if (tid < 128) ys[tid] = y[bm * 128 + tid];

    const int wave = tid >> 6;
    const int lane = tid & 63;
    const int wm   = wave >> 1;     // 0..1
    const int wn   = wave & 1;      // 0..1
    const int quad = lane >> 4;     // 0..3
    const int l15  = lane & 15;

    f32x4 acc[4][4];
    #pragma unroll
    for (int i = 0; i < 4; ++i)
        #pragma unroll
        for (int j = 0; j < 4; ++j) acc[i][j] = (f32x4){0.f, 0.f, 0.f, 0.f};
    float ssq[4] = {0.f, 0.f, 0.f, 0.f};

    // stage tile kt_ into buffer s.
    // A: 512 x 16B chunks, chunk c -> quad=c>>7, row=c&127
    // B: 1024 x 16B chunks, chunk c -> quad=c>>8, row=(c>>1)&127, half=c&1
    #define STAGE(s, kt_) do {                                                          \
        const int k0_ = (kt_) * 32;                                                     \
        _Pragma("unroll")                                                               \
        for (int i_ = 0; i_ < 2; ++i_) {                                                \
            const int c_ = tid + i_ * 256;                                              \
            const int qc_ = c_ >> 7, rc_ = c_ & 127;                                    \
            async_copy16(xn + (size_t)(bm * 128 + rc_) * D_FEAT + k0_ + qc_ * 8,        \
                         &As[s][c_ * 8]);                                               \
        }                                                                               \
        _Pragma("unroll")                                                               \
        for (int i_ = 0; i_ < 4; ++i_) {                                                \
            const int c_ = tid + i_ * 256;                                              \
            const int qc_ = c_ >> 8, rc_ = (c_ >> 1) & 127, hc_ = c_ & 1;               \
            int grow_ = bn * 128 + rc_; if (grow_ > C_CLS - 1) grow_ = C_CLS - 1;       \
            async_copy16(w + (size_t)grow_ * D_FEAT + k0_ + qc_ * 8 + hc_ * 4,          \
                         &Bs[s][c_ * 4]);                                               \
        }                                                                               \
    } while (0)

    STAGE(0, 0);       // 6 global_load_lds per thread per tile
    STAGE(1, 1);

    #pragma unroll
    for (int kt = 0; kt < 16; ++kt) {
        const int cur = kt & 1;

        // wait for tile kt's 6 loads (tile kt+1's 6 stay in flight), then barrier
        if (kt < 15) asm volatile("s_waitcnt vmcnt(6)" ::: "memory");
        else         asm volatile("s_waitcnt vmcnt(0)" ::: "memory");
        __builtin_amdgcn_s_barrier();

        bf16x8 af[4];
        #pragma unroll
        for (int mi = 0; mi < 4; ++mi)
            af[mi] = *(const bf16x8*)&As[cur][(quad * 128 + wm * 64 + mi * 16 + l15) * 8];

        bf16x8 bfr[4];
        #pragma unroll
        for (int ni = 0; ni < 4; ++ni) {
            const float* bp = &Bs[cur][(quad * 128 + wn * 64 + ni * 16 + l15) * 8];
            f32x4 b0 = *(const f32x4*)bp;
            f32x4 b1 = *(const f32x4*)(bp + 4);
            // inline weight-row sum of squares (this lane's k-slice of row)
            ssq[ni] += b0[0]*b0[0] + b0[1]*b0[1] + b0[2]*b0[2] + b0[3]*b0[3]
                     + b1[0]*b1[0] + b1[1]*b1[1] + b1[2]*b1[2] + b1[3]*b1[3];
            bf16x8 t;
            t[0] = (__bf16)b0[0]; t[1] = (__bf16)b0[1]; t[2] = (__bf16)b0[2]; t[3] = (__bf16)b0[3];
            t[4] = (__bf16)b1[0]; t[5] = (__bf16)b1[1]; t[6] = (__bf16)b1[2]; t[7] = (__bf16)b1[3];
            bfr[ni] = t;
        }

        // all reads of buf[cur] retired -> safe to restage it
        asm volatile("s_waitcnt lgkmcnt(0)" ::: "memory");
        __builtin_amdgcn_s_barrier();
        if (kt < 14) STAGE(cur, kt + 2);

        #pragma unroll
        for (int mi = 0; mi < 4; ++mi)
            #pragma unroll
            for (int ni = 0; ni < 4; ++ni)
                acc[mi][ni] = __builtin_amdgcn_mfma_f32_16x16x32_bf16(af[mi], bfr[ni], acc[mi][ni], 0, 0, 0);
    }
    #undef STAGE

    // ---- finish norms: reduce ssq across the 4 quad lanes (k-chunks) ----
    float invw[4];
    #pragma unroll
    for (int ni = 0; ni < 4; ++ni) {
        float s = ssq[ni];
        s += __shfl_xor(s, 16, 64);
        s += __shfl_xor(s, 32, 64);
        invw[ni] = 1.0f / fmaxf(sqrtf(s), 1e-12f);
    }

    // ---- epilogue: cos -> margin -> exp(logit-64) -> per-row partials ----
    #pragma unroll
    for (int mi = 0; mi < 4; ++mi) {
        float rs[4] = {0.f, 0.f, 0.f, 0.f};
        #pragma unroll
        for (int ni = 0; ni < 4; ++ni) {
            const int gcol = bn * 128 + wn * 64 + ni * 16 + l15;
            const bool colv = (gcol < C_CLS);
            #pragma unroll
            for (int reg = 0; reg < 4; ++reg) {
                const int lrow = wm * 64 + mi * 16 + quad * 4 + reg;
                const float cosv = acc[mi][ni][reg] * invw[ni];
                const float sinv = sqrtf(fmaxf(1.0f - cosv * cosv, 0.0f));
                const float phi  = (cosv > TH_) ? (cosv * COSM - sinv * SINM) : (cosv - MM_);
                const bool ist   = colv && (gcol == ys[lrow]);
                const float logit = 64.0f * (ist ? phi : cosv);
                if (ist) tlogit[bm * 128 + lrow] = logit;
                rs[reg] += colv ? __expf(logit - 64.0f) : 0.0f;
            }
        }
        #pragma unroll
        for (int reg = 0; reg < 4; ++reg) {
            float v = rs[reg];
            v += __shfl_xor(v, 8, 64);
            v += __shfl_xor(v, 4, 64);
            v += __shfl_xor(v, 2, 64);
            v += __shfl_xor(v, 1, 64);
            if (l15 == 0) red[wn][wm * 64 + mi * 16 + quad * 4 + reg] = v;
        }
    }
    __syncthreads();
    if (tid < 128) {
        const float v = red[0][tid] + red[1][tid];
        psum[(size_t)(bm * 128 + tid) * NBN + bn] = v;
    }
}

// ---------------- kernel 3: per-row reduce + loss -------------------------
__global__ void k_final(const float* __restrict__ psum, const float* __restrict__ tlogit,
                        float* __restrict__ out) {
    const int row = blockIdx.x * 4 + (threadIdx.x >> 6);   // 128 blocks x 4 rows
    const int l   = threadIdx.x & 63;
    const float* p = psum + (size_t)row * NBN;
    float s = 0.0f;
    for (int i = l; i < NBN; i += 64) s += p[i];
    #pragma unroll
    for (int m = 32; m >= 1; m >>= 1) s += __shfl_xor(s, m, 64);
    if (l == 0) {
        const float loss = logf(s) + 64.0f - tlogit[row];
        atomicAdd(out, loss * (1.0f / 512.0f));
    }
}

extern "C" void kernel_launch(void* const* d_in, const int* in_sizes, int n_in,
                              void* d_out, int out_size, void* d_ws, size_t ws_size,
                              hipStream_t stream) {
    const float* x = (const float*)d_in[0];
    const int*   y = (const int*)d_in[1];
    const float* w = (const float*)d_in[2];

    char* ws = (char*)d_ws;
    __bf16* xn     = (__bf16*)ws;                               // 524288 B
    float*  psum   = (float*)(ws + 524288);                     // 512*782*4 = 1601536 B
    float*  tlogit = (float*)(ws + 524288 + 1601536);           // 2048 B
    float*  out    = (float*)d_out;

    hipLaunchKernelGGL(k_xnorm, dim3(512), dim3(64), 0, stream, x, xn, out);
    hipLaunchKernelGGL(k_gemm, dim3(4 * NBN), dim3(256), 0, stream, xn, w, y, psum, tlogit);
    hipLaunchKernelGGL(k_final, dim3(128), dim3(256), 0, stream, psum, tlogit, out);
}